// Round 1
// 698.305 us; speedup vs baseline: 1.0283x; 1.0283x over previous
//
#include <hip/hip_runtime.h>

#define DM 1024
#define NHEADS 16
#define DK 64
#define BSZ 2
#define NSEQ 8192
#define MROWS (BSZ*NSEQ)
#define NCHUNKS 16
#define CHUNKN 512

typedef unsigned short u16;
typedef __attribute__((ext_vector_type(8))) short short8;
typedef __attribute__((ext_vector_type(4))) float f32x4;

constexpr float EPS_F = 1e-6f;

__device__ __forceinline__ u16 f2bf(float x) {
  union { float f; unsigned u; } c; c.f = x;
  unsigned r = c.u + 0x7FFFu + ((c.u >> 16) & 1u);
  return (u16)(r >> 16);
}
__device__ __forceinline__ float bf2f(u16 h) {
  union { unsigned u; float f; } c; c.u = ((unsigned)h) << 16;
  return c.f;
}

typedef __attribute__((address_space(1))) const void gvoid_t;
typedef __attribute__((address_space(3))) void lvoid_t;
__device__ __forceinline__ void gl2lds16(const void* g, void* l) {
  // width=16: global_load_lds_dwordx4; LDS dst = wave-uniform base + lane*16
  __builtin_amdgcn_global_load_lds((gvoid_t*)g, (lvoid_t*)l, 16, 0, 0);
}

// fp32 -> (hi bf16, lo bf16) split.  hi = rne(x), lo = rne(x - hi).
__global__ __launch_bounds__(256)
void split_kernel(const float* __restrict__ src, u16* __restrict__ hi,
                  u16* __restrict__ lo, int n4) {
  int i = blockIdx.x * 256 + threadIdx.x;
  const int stride = gridDim.x * 256;
  for (; i < n4; i += stride) {
    const float4 v = ((const float4*)src)[i];
    const u16 h0 = f2bf(v.x), h1 = f2bf(v.y), h2 = f2bf(v.z), h3 = f2bf(v.w);
    const u16 l0 = f2bf(v.x - bf2f(h0)), l1 = f2bf(v.y - bf2f(h1));
    const u16 l2 = f2bf(v.z - bf2f(h2)), l3 = f2bf(v.w - bf2f(h3));
    ((ushort4*)hi)[i] = make_ushort4(h0, h1, h2, h3);
    ((ushort4*)lo)[i] = make_ushort4(l0, l1, l2, l3);
  }
}

// All four 1024x1024 weights split in one launch; also zeroes ksum (2048 f32).
__global__ __launch_bounds__(256)
void wsplit_kernel(const float* __restrict__ w0, const float* __restrict__ w1,
                   const float* __restrict__ w2, const float* __restrict__ w3,
                   u16* __restrict__ h0, u16* __restrict__ l0,
                   u16* __restrict__ h1, u16* __restrict__ l1,
                   u16* __restrict__ h2, u16* __restrict__ l2,
                   u16* __restrict__ h3, u16* __restrict__ l3,
                   float* __restrict__ ksum) {
  if (blockIdx.x < 8) ksum[blockIdx.x * 256 + threadIdx.x] = 0.f;
  constexpr int per = DM * DM / 4;   // 2^18 float4s per weight
  int i = blockIdx.x * 256 + threadIdx.x;
  const int stride = gridDim.x * 256;
  for (; i < 4 * per; i += stride) {
    const int w = i >> 18, j = i & (per - 1);
    const float* src = w == 0 ? w0 : w == 1 ? w1 : w == 2 ? w2 : w3;
    u16* hi = w == 0 ? h0 : w == 1 ? h1 : w == 2 ? h2 : h3;
    u16* lo = w == 0 ? l0 : w == 1 ? l1 : w == 2 ? l2 : l3;
    const float4 v = ((const float4*)src)[j];
    const u16 a0 = f2bf(v.x), a1 = f2bf(v.y), a2 = f2bf(v.z), a3 = f2bf(v.w);
    ((ushort4*)hi)[j] = make_ushort4(a0, a1, a2, a3);
    ((ushort4*)lo)[j] = make_ushort4(f2bf(v.x - bf2f(a0)), f2bf(v.y - bf2f(a1)),
                                     f2bf(v.z - bf2f(a2)), f2bf(v.w - bf2f(a3)));
  }
}

// C[M x N] = (Ahi+Alo)[M x K] @ (Whi+Wlo)[N x K]^T + bias via 3 bf16 MFMA
// passes (hi*hi + hi*lo + lo*hi).
//
// 256x256 tile, BK=32, 512 threads = 8 waves (2M x 4N), wave tile 128x64.
// 8-phase-style schedule (m201/T3+T4+T5): double-buffered LDS (128 KB,
// 1 block/CU), all 8 global_load_lds issued at K-step top, COUNTED
// s_waitcnt vmcnt(8) (never 0 in-loop) + raw s_barrier -- prefetch stays in
// flight across the whole compute.  6 phases x 16 MFMA, each phase
// {ds_read cluster; barrier; setprio(1); MFMA; setprio(0); barrier}.
// T2 swizzle both-sides (rule #21): LDS linear for gl2lds, 2-bit column-slot
// XOR (kslot ^= row&3) applied to the per-lane GLOBAL source address at
// staging and to the ds_read offset -> each 8-lane read group spreads over
// 4 bank-quads (2-way, free) instead of 2 (was 8.4M SQ_LDS_BANK_CONFLICT).
// lgkmcnt(0)+sched_barrier(0) before the iteration's last barrier closes the
// in-flight-ds_read vs next-STAGE-overwrite race (rule #18).
// MODE: 0 = f32 normal, 1 = bf16 normal, 2 = bf16 transposed (C^T[N][M]),
//       3 = bf16 transposed + ksum column-sum atomics (for K projection).
template<int ACT, int MODE>
__global__ __launch_bounds__(512, 2)
void gemm_mfma_kernel(const u16* __restrict__ Ahi, const u16* __restrict__ Alo,
                      const u16* __restrict__ Whi, const u16* __restrict__ Wlo,
                      const float* __restrict__ bias, void* __restrict__ Cout,
                      float* __restrict__ ksum) {
  constexpr int K = DM, N = DM, BK = 32, NT = K / BK;
  // lds[buf][stream][2 halves x 128 rows x 32 k]  (streams: Ahi,Alo,Whi,Wlo)
  __shared__ u16 lds[2 * 4 * 8192];   // 128 KiB
  const int tid = threadIdx.x;
  const int lane = tid & 63, wv = tid >> 6;
  const int bRow = blockIdx.y * 256, bCol = blockIdx.x * 256;

  // --- staging geometry: thread tid owns LDS slot tid (16B) of each chunk:
  //     row = tid>>2 (within 128-row half), linear kslot = tid&3.
  //     Source-side swizzle: fetch global kslot kg = (tid&3) ^ (row&3), so
  //     the linear gl2lds write realizes the swizzled layout.
  const int srow = tid >> 2;
  const int kg = (tid & 3) ^ (srow & 3);
  const unsigned oA0 = (unsigned)(bRow + srow) * K + kg * 8;
  const unsigned oA1 = oA0 + 128u * K;
  const unsigned oW0 = (unsigned)(bCol + srow) * K + kg * 8;
  const unsigned oW1 = oW0 + 128u * K;

  // --- fragment-read geometry (swizzled): element (row, kslot=lane>>4) is
  //     at u16 offset row*32 + ((lane>>4) ^ (row&3))*8 ; row&3 == fr&3.
  const int wr = wv >> 2, wc = wv & 3;          // wave -> 128x64 sub-tile
  const int fr = lane & 15;
  const int axor = ((lane >> 4) ^ (fr & 3)) * 8;
  const int aoff = (wr * 128 + fr) * 32 + axor; // A-stream read base (u16)
  const int woff = (wc * 64 + fr) * 32 + axor;  // W-stream read base (u16)

  f32x4 acc[8][4] = {};

  auto STAGE = [&](int buf, int k0) {
    u16* b = lds + buf * 32768 + wv * 512;      // wave-uniform LDS dst
    gl2lds16(Ahi + oA0 + k0, b);
    gl2lds16(Ahi + oA1 + k0, b + 4096);
    gl2lds16(Alo + oA0 + k0, b + 8192);
    gl2lds16(Alo + oA1 + k0, b + 12288);
    gl2lds16(Whi + oW0 + k0, b + 16384);
    gl2lds16(Whi + oW1 + k0, b + 20480);
    gl2lds16(Wlo + oW0 + k0, b + 24576);
    gl2lds16(Wlo + oW1 + k0, b + 28672);
  };

  STAGE(0, 0);
  for (int t = 0; t < NT; ++t) {
    const int cur = t & 1;
    if (t + 1 < NT) {
      STAGE(cur ^ 1, (t + 1) * BK);
      // counted wait: 16 outstanding -> wait oldest 8 (cur buffer) only;
      // the 8 just-issued loads stay in flight under this K-step's compute.
      asm volatile("s_waitcnt vmcnt(8)" ::: "memory");
    } else {
      asm volatile("s_waitcnt vmcnt(0)" ::: "memory");
    }
    __builtin_amdgcn_s_barrier();

    const u16* A0 = lds + cur * 32768;
    const u16* A1 = A0 + 8192;
    const u16* W0 = A0 + 16384;
    const u16* W1 = A0 + 24576;

    short8 ah[4], al[4], bh[4], bl[4];
    auto LDF = [&](short8 (&f)[4], const u16* s, int off) {
#pragma unroll
      for (int i = 0; i < 4; i++) f[i] = *(const short8*)(s + off + i * 512);
    };
    auto MM = [&](short8 (&af)[4], short8 (&bf)[4], int mb) {
      __builtin_amdgcn_s_setprio(1);
#pragma unroll
      for (int mt = 0; mt < 4; mt++)
#pragma unroll
        for (int nt = 0; nt < 4; nt++)
          acc[mb + mt][nt] = __builtin_amdgcn_mfma_f32_16x16x32_bf16(
              af[mt], bf[nt], acc[mb + mt][nt], 0, 0, 0);
      __builtin_amdgcn_s_setprio(0);
    };

    // P1: hi*hi, rows 0-63 of wave tile
    LDF(ah, A0, aoff); LDF(bh, W0, woff);
    __builtin_amdgcn_s_barrier();
    MM(ah, bh, 0);
    __builtin_amdgcn_s_barrier();
    // P2: hi*lo
    LDF(bl, W1, woff);
    __builtin_amdgcn_s_barrier();
    MM(ah, bl, 0);
    __builtin_amdgcn_s_barrier();
    // P3: lo*hi
    LDF(al, A1, aoff);
    __builtin_amdgcn_s_barrier();
    MM(al, bh, 0);
    __builtin_amdgcn_s_barrier();
    // P4: hi*hi, rows 64-127
    LDF(ah, A0, aoff + 2048);
    __builtin_amdgcn_s_barrier();
    MM(ah, bh, 4);
    __builtin_amdgcn_s_barrier();
    // P5: hi*lo (no new reads)
    MM(ah, bl, 4);
    __builtin_amdgcn_s_barrier();
    // P6: lo*hi
    LDF(al, A1, aoff + 2048);
    __builtin_amdgcn_s_barrier();
    MM(al, bh, 4);
    // drain our ds_reads before the barrier that releases next STAGE into cur
    asm volatile("s_waitcnt lgkmcnt(0)" ::: "memory");
    __builtin_amdgcn_sched_barrier(0);
    __builtin_amdgcn_s_barrier();
  }

  // epilogue: C/D layout col = lane&15, row = (lane>>4)*4 + reg  [m89]
  const int erow = (lane >> 4) * 4;
  const int ecol = lane & 15;
  float bvv[4];
#pragma unroll
  for (int nt = 0; nt < 4; nt++) bvv[nt] = bias[bCol + wc * 64 + nt * 16 + ecol];
  float csum[4] = {0.f, 0.f, 0.f, 0.f};
#pragma unroll
  for (int mt = 0; mt < 8; mt++)
#pragma unroll
    for (int nt = 0; nt < 4; nt++)
#pragma unroll
      for (int r = 0; r < 4; r++) {
        const size_t row = (size_t)bRow + wr * 128 + mt * 16 + erow + r;
        const size_t col = (size_t)bCol + wc * 64 + nt * 16 + ecol;
        float v = acc[mt][nt][r] + bvv[nt];
        if (ACT) v = v > 0.f ? (v + 1.f) : __expf(v);  // elu(x)+1
        if (MODE == 0)      ((float*)Cout)[row * N + col] = v;
        else if (MODE == 1) ((u16*)Cout)[row * N + col] = f2bf(v);
        else {
          ((u16*)Cout)[col * (size_t)MROWS + row] = f2bf(v);  // C^T
          if (MODE == 3) csum[nt] += v;
        }
      }
  if (MODE == 3) {
    const int bidx = bRow >> 13;  // 256-row strip never crosses batch
#pragma unroll
    for (int nt = 0; nt < 4; nt++) {
      float s = csum[nt];
      s += __shfl_xor(s, 16, 64);
      s += __shfl_xor(s, 32, 64);   // quads hold the wave's 128-row col sum
      if ((lane >> 4) == 0)
        atomicAdd(&ksum[bidx * DM + bCol + wc * 64 + nt * 16 + ecol], s);
    }
  }
}

// KVT[m][d] partial = sum_n vT[m][n]*kT[d][n] over this block's 512-n chunk.
__global__ __launch_bounds__(256)
void kv_mfma_kernel(const u16* __restrict__ kT, const u16* __restrict__ vT,
                    float* __restrict__ part) {
  const int bh = blockIdx.y;
  const int b = bh >> 4, h = bh & 15;
  const size_t colbase = (size_t)b * NSEQ + blockIdx.x * CHUNKN;
  __shared__ u16 kts[64 * 64], vts[64 * 64];
  const int tid = threadIdx.x, lane = tid & 63, w = tid >> 6;
  const int wm = (w & 1) * 32, wd = (w >> 1) * 32;
  const int fr = lane & 15, fk = (lane >> 4) * 8;
  const int srow = lane >> 3, scol = (lane & 7) * 8;

  f32x4 acc[2][2] = {};

  for (int s = 0; s < CHUNKN / 64; s++) {
    const size_t cb = colbase + s * 64 + scol;
#pragma unroll
    for (int i = 0; i < 2; i++) {
      const int ii = w * 2 + i;
      const size_t grow = (size_t)(h * DK + ii * 8 + srow) * MROWS + cb;
      gl2lds16(vT + grow, vts + ii * 512);
      gl2lds16(kT + grow, kts + ii * 512);
    }
    __syncthreads();
#pragma unroll
    for (int ks = 0; ks < 2; ks++) {
      short8 af[2], bfr[2];
#pragma unroll
      for (int mt = 0; mt < 2; mt++)
        af[mt] = *(const short8*)(vts + (wm + mt * 16 + fr) * 64 + ks * 32 + fk);
#pragma unroll
      for (int dt = 0; dt < 2; dt++)
        bfr[dt] = *(const short8*)(kts + (wd + dt * 16 + fr) * 64 + ks * 32 + fk);
#pragma unroll
      for (int mt = 0; mt < 2; mt++)
#pragma unroll
        for (int dt = 0; dt < 2; dt++)
          acc[mt][dt] = __builtin_amdgcn_mfma_f32_16x16x32_bf16(af[mt], bfr[dt], acc[mt][dt], 0, 0, 0);
    }
    __syncthreads();
  }

  float* pp = part + ((size_t)blockIdx.x * 32 + bh) * (DK * DK);
  const int erow = (lane >> 4) * 4, ecol = lane & 15;
#pragma unroll
  for (int mt = 0; mt < 2; mt++)
#pragma unroll
    for (int dt = 0; dt < 2; dt++)
#pragma unroll
      for (int r = 0; r < 4; r++)
        pp[(wm + mt * 16 + erow + r) * DK + wd + dt * 16 + ecol] = acc[mt][dt][r];
}

// Reduce the 16 chunk-partials -> bf16 KVT[bh][m][d].
__global__ __launch_bounds__(256)
void kvt_reduce_kernel(const float* __restrict__ part, u16* __restrict__ kvt) {
  const int bh = blockIdx.x, t = threadIdx.x;
  const int i0 = t * 16;
  f32x4 s[4] = {};
  for (int c = 0; c < NCHUNKS; c++) {
    const f32x4* p = (const f32x4*)(part + ((size_t)c * 32 + bh) * (DK * DK) + i0);
#pragma unroll
    for (int q = 0; q < 4; q++) s[q] += p[q];
  }
  short8 o[2];
#pragma unroll
  for (int j = 0; j < 16; j++) o[j >> 3][j & 7] = (short)f2bf(s[j >> 2][j & 3]);
  *(short8*)(kvt + (size_t)bh * (DK * DK) + i0) = o[0];
  *(short8*)(kvt + (size_t)bh * (DK * DK) + i0 + 8) = o[1];
}

// out[n][m] = (q[n][:] . KVT[m][:]) / (q[n][:] . ksum + eps), per (b,h).
__global__ __launch_bounds__(256)
void attn_mfma_kernel(const u16* __restrict__ qp, const u16* __restrict__ kvt,
                      const float* __restrict__ ksum,
                      u16* __restrict__ ahi, u16* __restrict__ alo) {
  const int bh = blockIdx.y;
  const int b = bh >> 4, h = bh & 15;
  const int n0 = blockIdx.x * 128;
  const int tid = threadIdx.x, lane = tid & 63, w = tid >> 6;
  const int fr = lane & 15, fk = (lane >> 4) * 8;
  __shared__ float norm_lds[128];

  short8 bfr[4][2];
#pragma unroll
  for (int mt = 0; mt < 4; mt++)
#pragma unroll
    for (int ks = 0; ks < 2; ks++)
      bfr[mt][ks] = *(const short8*)(kvt + (size_t)bh * (DK * DK) + (mt * 16 + fr) * DK + ks * 32 + fk);

  float ksf[2][8];
#pragma unroll
  for (int ks = 0; ks < 2; ks++)
#pragma unroll
    for (int j = 0; j < 8; j++)
      ksf[ks][j] = ksum[b * DM + h * DK + ks * 32 + fk + j];

  const int nb = n0 + w * 32;
  short8 af[2][2];
#pragma unroll
  for (int nt = 0; nt < 2; nt++)
#pragma unroll
    for (int ks = 0; ks < 2; ks++)
      af[nt][ks] = *(const short8*)(qp + (size_t)(b * NSEQ + nb + nt * 16 + fr) * DM + h * DK + ks * 32 + fk);

  f32x4 acc[2][4] = {};
#pragma unroll
  for (int nt = 0; nt < 2; nt++)
#pragma unroll
    for (int mt = 0; mt < 4; mt++)
#pragma unroll
      for (int ks = 0; ks < 2; ks++)
        acc[nt][mt] = __builtin_amdgcn_mfma_f32_16x16x32_bf16(af[nt][ks], bfr[mt][ks], acc[nt][mt], 0, 0, 0);

#pragma unroll
  for (int nt = 0; nt < 2; nt++) {
    float p = 0.f;
#pragma unroll
    for (int ks = 0; ks < 2; ks++)
#pragma unroll
      for (int j = 0; j < 8; j++)
        p += bf2f((u16)af[nt][ks][j]) * ksf[ks][j];
    p += __shfl_xor(p, 16, 64);
    p += __shfl_xor(p, 32, 64);
    if ((lane >> 4) == 0) norm_lds[w * 32 + nt * 16 + fr] = p + EPS_F;
  }
  __syncthreads();

  const int erow = (lane >> 4) * 4, ec = lane & 15;
#pragma unroll
  for (int nt = 0; nt < 2; nt++) {
    float inv[4];
#pragma unroll
    for (int r = 0; r < 4; r++) inv[r] = 1.f / norm_lds[w * 32 + nt * 16 + erow + r];
#pragma unroll
    for (int mt = 0; mt < 4; mt++)
#pragma unroll
      for (int r = 0; r < 4; r++) {
        const float v = acc[nt][mt][r] * inv[r];
        const size_t o = (size_t)(b * NSEQ + nb + nt * 16 + erow + r) * DM + h * DK + mt * 16 + ec;
        const u16 hh = f2bf(v);
        ahi[o] = hh;
        alo[o] = f2bf(v - bf2f(hh));
      }
  }
}

extern "C" void kernel_launch(void* const* d_in, const int* in_sizes, int n_in,
                              void* d_out, int out_size, void* d_ws, size_t ws_size,
                              hipStream_t stream) {
  const float* query = (const float*)d_in[0];
  const float* key   = (const float*)d_in[1];
  const float* value = (const float*)d_in[2];
  const float* wq = (const float*)d_in[3];
  const float* bq = (const float*)d_in[4];
  const float* wk = (const float*)d_in[5];
  const float* bk = (const float*)d_in[6];
  const float* wv = (const float*)d_in[7];
  const float* bv = (const float*)d_in[8];
  const float* wo = (const float*)d_in[9];
  const float* bo = (const float*)d_in[10];
  float* out = (float*)d_out;

  constexpr size_t WELEM = (size_t)DM * DM;
  constexpr size_t AELEM = (size_t)MROWS * DM;

  char* p = (char*)d_ws;
  auto take = [&](size_t bytes) { char* q = p; p += (bytes + 255) & ~(size_t)255; return q; };
  u16* wqh = (u16*)take(WELEM * 2); u16* wql = (u16*)take(WELEM * 2);
  u16* wkh = (u16*)take(WELEM * 2); u16* wkl = (u16*)take(WELEM * 2);
  u16* wvh = (u16*)take(WELEM * 2); u16* wvl = (u16*)take(WELEM * 2);
  u16* woh = (u16*)take(WELEM * 2); u16* wol = (u16*)take(WELEM * 2);
  u16* chi = (u16*)take(AELEM * 2); u16* clo = (u16*)take(AELEM * 2);
  u16* qp  = (u16*)take(AELEM * 2);
  u16* kT  = (u16*)take(AELEM * 2);
  u16* vT  = (u16*)take(AELEM * 2);
  float* part = (float*)take((size_t)NCHUNKS * 32 * DK * DK * 4);
  float* ksum = (float*)take((size_t)BSZ * DM * 4);
  u16* kvt = (u16*)take((size_t)BSZ * NHEADS * DK * DK * 2);
  u16* ahi = chi; u16* alo = clo;   // chi/clo dead after V-GEMM reads them

  const dim3 blk(256);
  wsplit_kernel<<<1024, blk, 0, stream>>>(wq, wk, wv, wo, wqh, wql, wkh, wkl,
                                          wvh, wvl, woh, wol, ksum);

  const dim3 gblk(512);
  const dim3 ggrid(DM / 256, MROWS / 256);   // 4 x 64 = 256 blocks = 1/CU
  split_kernel<<<2048, blk, 0, stream>>>(query, chi, clo, (int)(AELEM / 4));
  gemm_mfma_kernel<1, 1><<<ggrid, gblk, 0, stream>>>(chi, clo, wqh, wql, bq, qp, nullptr);
  split_kernel<<<2048, blk, 0, stream>>>(key, chi, clo, (int)(AELEM / 4));
  gemm_mfma_kernel<1, 3><<<ggrid, gblk, 0, stream>>>(chi, clo, wkh, wkl, bk, kT, ksum);
  split_kernel<<<2048, blk, 0, stream>>>(value, chi, clo, (int)(AELEM / 4));
  gemm_mfma_kernel<0, 2><<<ggrid, gblk, 0, stream>>>(chi, clo, wvh, wvl, bv, vT, nullptr);

  kv_mfma_kernel<<<dim3(NCHUNKS, BSZ * NHEADS), blk, 0, stream>>>(kT, vT, part);
  kvt_reduce_kernel<<<32, blk, 0, stream>>>(part, kvt);
  attn_mfma_kernel<<<dim3(NSEQ / 128, BSZ * NHEADS), blk, 0, stream>>>(qp, kvt, ksum, ahi, alo);
  gemm_mfma_kernel<0, 0><<<ggrid, gblk, 0, stream>>>(ahi, alo, woh, wol, bo, out, nullptr);
}

// Round 2
// 660.352 us; speedup vs baseline: 1.0874x; 1.0575x over previous
//
#include <hip/hip_runtime.h>

#define DM 1024
#define NHEADS 16
#define DK 64
#define BSZ 2
#define NSEQ 8192
#define MROWS (BSZ*NSEQ)
#define NCHUNKS 16
#define CHUNKN 512

typedef unsigned short u16;
typedef __attribute__((ext_vector_type(8))) short short8;
typedef __attribute__((ext_vector_type(4))) float f32x4;

constexpr float EPS_F = 1e-6f;

__device__ __forceinline__ u16 f2bf(float x) {
  union { float f; unsigned u; } c; c.f = x;
  unsigned r = c.u + 0x7FFFu + ((c.u >> 16) & 1u);
  return (u16)(r >> 16);
}
__device__ __forceinline__ float bf2f(u16 h) {
  union { unsigned u; float f; } c; c.u = ((unsigned)h) << 16;
  return c.f;
}

typedef __attribute__((address_space(1))) const void gvoid_t;
typedef __attribute__((address_space(3))) void lvoid_t;
__device__ __forceinline__ void gl2lds16(const void* g, void* l) {
  // width=16: global_load_lds_dwordx4; LDS dst = wave-uniform base + lane*16
  __builtin_amdgcn_global_load_lds((gvoid_t*)g, (lvoid_t*)l, 16, 0, 0);
}

// fp32 -> (hi bf16, lo bf16) split.  hi = rne(x), lo = rne(x - hi).
__global__ __launch_bounds__(256)
void split_kernel(const float* __restrict__ src, u16* __restrict__ hi,
                  u16* __restrict__ lo, int n4) {
  int i = blockIdx.x * 256 + threadIdx.x;
  const int stride = gridDim.x * 256;
  for (; i < n4; i += stride) {
    const float4 v = ((const float4*)src)[i];
    const u16 h0 = f2bf(v.x), h1 = f2bf(v.y), h2 = f2bf(v.z), h3 = f2bf(v.w);
    const u16 l0 = f2bf(v.x - bf2f(h0)), l1 = f2bf(v.y - bf2f(h1));
    const u16 l2 = f2bf(v.z - bf2f(h2)), l3 = f2bf(v.w - bf2f(h3));
    ((ushort4*)hi)[i] = make_ushort4(h0, h1, h2, h3);
    ((ushort4*)lo)[i] = make_ushort4(l0, l1, l2, l3);
  }
}

// All four 1024x1024 weights split in one launch; also zeroes ksum (2048 f32).
__global__ __launch_bounds__(256)
void wsplit_kernel(const float* __restrict__ w0, const float* __restrict__ w1,
                   const float* __restrict__ w2, const float* __restrict__ w3,
                   u16* __restrict__ h0, u16* __restrict__ l0,
                   u16* __restrict__ h1, u16* __restrict__ l1,
                   u16* __restrict__ h2, u16* __restrict__ l2,
                   u16* __restrict__ h3, u16* __restrict__ l3,
                   float* __restrict__ ksum) {
  if (blockIdx.x < 8) ksum[blockIdx.x * 256 + threadIdx.x] = 0.f;
  constexpr int per = DM * DM / 4;   // 2^18 float4s per weight
  int i = blockIdx.x * 256 + threadIdx.x;
  const int stride = gridDim.x * 256;
  for (; i < 4 * per; i += stride) {
    const int w = i >> 18, j = i & (per - 1);
    const float* src = w == 0 ? w0 : w == 1 ? w1 : w == 2 ? w2 : w3;
    u16* hi = w == 0 ? h0 : w == 1 ? h1 : w == 2 ? h2 : h3;
    u16* lo = w == 0 ? l0 : w == 1 ? l1 : w == 2 ? l2 : l3;
    const float4 v = ((const float4*)src)[j];
    const u16 a0 = f2bf(v.x), a1 = f2bf(v.y), a2 = f2bf(v.z), a3 = f2bf(v.w);
    ((ushort4*)hi)[j] = make_ushort4(a0, a1, a2, a3);
    ((ushort4*)lo)[j] = make_ushort4(f2bf(v.x - bf2f(a0)), f2bf(v.y - bf2f(a1)),
                                     f2bf(v.z - bf2f(a2)), f2bf(v.w - bf2f(a3)));
  }
}

// C[M x N] = (Ahi+Alo)[M x K] @ (Whi+Wlo)[N x K]^T + bias via 3 bf16 MFMA
// passes (hi*hi + hi*lo + lo*hi).
//
// 256x256 tile, BK=32, 512 threads = 8 waves (2M x 4N), wave tile 128x64.
// Schedule: double-buffered LDS (128 KB, 1 block/CU), 8 global_load_lds
// issued at K-step top, COUNTED s_waitcnt vmcnt(8) (never 0 in-loop) + raw
// s_barrier.  5 phases/K-step, ONE closing barrier per phase (intra-step
// barriers are perf-only: frags are wave-private; correctness needs only the
// vmcnt barrier + the lgkm(0)-closed iteration end before STAGE overwrites).
//
// T1: XCD-aware tile remap (bijective, 256%8==0): all 4 column-blocks of an
//     A-strip land on one XCD -> A staging is L2-resident (was 2x HBM fetch).
// T2: LDS swizzle kslot ^= (row>>1)&3 BOTH sides (source addr + read offset).
//     Quarter-phase quad = (fr&1)*4 + ((fr>>1)&3): all 8 bank-quads hit
//     exactly 2x per 16 lanes = conflict-free minimum for b128.
//     (round-1's row&3 XOR left 4-way quarter-phase conflicts: fr&3 of even
//     lanes only spans {0,2}.)
// MODE: 0 = f32 normal, 1 = bf16 normal, 2 = bf16 transposed (C^T[N][M]),
//       3 = bf16 transposed + ksum column-sum atomics (for K projection).
template<int ACT, int MODE>
__global__ __launch_bounds__(512, 2)
void gemm_mfma_kernel(const u16* __restrict__ Ahi, const u16* __restrict__ Alo,
                      const u16* __restrict__ Whi, const u16* __restrict__ Wlo,
                      const float* __restrict__ bias, void* __restrict__ Cout,
                      float* __restrict__ ksum) {
  constexpr int K = DM, N = DM, BK = 32, NT = K / BK;
  // lds[buf][stream: Ahi 256rows | Alo | Whi | Wlo][row][32k swizzled]
  __shared__ u16 lds[2 * 4 * 8192];   // 128 KiB
  const int tid = threadIdx.x;
  const int lane = tid & 63, wv = tid >> 6;

  // XCD-aware remap: hw linear bid -> tile id so XCD c (= bid%8) owns
  // tiles [32c, 32c+32) = 8 consecutive A-strips x all 4 column-blocks.
  const int bid = blockIdx.y * gridDim.x + blockIdx.x;
  const int tile = (bid & 7) * 32 + (bid >> 3);
  const int bx = tile & 3, by = tile >> 2;
  const int bRow = by * 256, bCol = bx * 256;

  // --- staging: thread tid owns LDS u16 slot tid*8 of each 8KB chunk:
  //     row = tid>>2 (within 128-row half), linear kslot = tid&3.
  //     Source-side swizzle: fetch global kslot kg = (tid&3) ^ ((row>>1)&3)
  //     so the linear gl2lds write realizes the swizzled layout.
  const int srow = tid >> 2;
  const int kg = (tid & 3) ^ ((srow >> 1) & 3);
  const unsigned oA0 = (unsigned)(bRow + srow) * K + kg * 8;
  const unsigned oA1 = oA0 + 128u * K;
  const unsigned oW0 = (unsigned)(bCol + srow) * K + kg * 8;
  const unsigned oW1 = oW0 + 128u * K;

  // --- fragment reads: element (row, kslot=lane>>4) lives at u16 offset
  //     row*32 + ((lane>>4) ^ ((row>>1)&3))*8 ; (row>>1)&3 == (fr>>1)&3
  //     since all row bases are multiples of 16.
  const int wr = wv >> 2, wc = wv & 3;          // wave -> 128x64 sub-tile
  const int fr = lane & 15;
  const int axor = ((lane >> 4) ^ ((fr >> 1) & 3)) * 8;
  const int aoff = (wr * 128 + fr) * 32 + axor; // A-stream read base (u16)
  const int woff = (wc * 64 + fr) * 32 + axor;  // W-stream read base (u16)

  f32x4 acc[8][4] = {};

  auto STAGE = [&](int buf, int k0) {
    u16* b = lds + buf * 32768 + wv * 512;      // wave-uniform LDS dst
    gl2lds16(Ahi + oA0 + k0, b);
    gl2lds16(Ahi + oA1 + k0, b + 4096);
    gl2lds16(Alo + oA0 + k0, b + 8192);
    gl2lds16(Alo + oA1 + k0, b + 12288);
    gl2lds16(Whi + oW0 + k0, b + 16384);
    gl2lds16(Whi + oW1 + k0, b + 20480);
    gl2lds16(Wlo + oW0 + k0, b + 24576);
    gl2lds16(Wlo + oW1 + k0, b + 28672);
  };

  STAGE(0, 0);
  for (int t = 0; t < NT; ++t) {
    const int cur = t & 1;
    if (t + 1 < NT) {
      STAGE(cur ^ 1, (t + 1) * BK);
      // counted wait: 16 outstanding -> wait oldest 8 (cur buffer) only;
      // the 8 just-issued loads stay in flight under this K-step's compute.
      asm volatile("s_waitcnt vmcnt(8)" ::: "memory");
    } else {
      asm volatile("s_waitcnt vmcnt(0)" ::: "memory");
    }
    __builtin_amdgcn_s_barrier();

    const u16* A0 = lds + cur * 32768;   // Ahi rows 0..255 (swizzled k)
    const u16* A1 = A0 + 8192;           // Alo
    const u16* W0 = A0 + 16384;          // Whi
    const u16* W1 = A0 + 24576;          // Wlo

    short8 ah[4], al[4], bh[4], bl[4];
    auto LDF = [&](short8 (&f)[4], const u16* s, int off) {
#pragma unroll
      for (int i = 0; i < 4; i++) f[i] = *(const short8*)(s + off + i * 512);
    };
    auto MM = [&](short8 (&af)[4], short8 (&bf)[4], int mb) {
      __builtin_amdgcn_s_setprio(1);
#pragma unroll
      for (int mt = 0; mt < 4; mt++)
#pragma unroll
        for (int nt = 0; nt < 4; nt++)
          acc[mb + mt][nt] = __builtin_amdgcn_mfma_f32_16x16x32_bf16(
              af[mt], bf[nt], acc[mb + mt][nt], 0, 0, 0);
      __builtin_amdgcn_s_setprio(0);
    };

    // P1: hi*hi, wave-rows 0-63
    LDF(ah, A0, aoff); LDF(bh, W0, woff);
    MM(ah, bh, 0);
    __builtin_amdgcn_s_barrier();
    // P2: hi*lo
    LDF(bl, W1, woff);
    MM(ah, bl, 0);
    __builtin_amdgcn_s_barrier();
    // P3: lo*hi
    LDF(al, A1, aoff);
    MM(al, bh, 0);
    __builtin_amdgcn_s_barrier();
    // P4: rows 64-127, hi*hi + hi*lo
    LDF(ah, A0, aoff + 2048);
    MM(ah, bh, 4);
    MM(ah, bl, 4);
    __builtin_amdgcn_s_barrier();
    // P5: rows 64-127, lo*hi
    LDF(al, A1, aoff + 2048);
    MM(al, bh, 4);
    // drain our ds_reads before the barrier that releases next STAGE into cur
    asm volatile("s_waitcnt lgkmcnt(0)" ::: "memory");
    __builtin_amdgcn_sched_barrier(0);
    __builtin_amdgcn_s_barrier();
  }

  // epilogue: C/D layout col = lane&15, row = (lane>>4)*4 + reg  [m89]
  const int erow = (lane >> 4) * 4;
  const int ecol = lane & 15;
  float bvv[4];
#pragma unroll
  for (int nt = 0; nt < 4; nt++) bvv[nt] = bias[bCol + wc * 64 + nt * 16 + ecol];
  float csum[4] = {0.f, 0.f, 0.f, 0.f};
#pragma unroll
  for (int mt = 0; mt < 8; mt++)
#pragma unroll
    for (int nt = 0; nt < 4; nt++)
#pragma unroll
      for (int r = 0; r < 4; r++) {
        const size_t row = (size_t)bRow + wr * 128 + mt * 16 + erow + r;
        const size_t col = (size_t)bCol + wc * 64 + nt * 16 + ecol;
        float v = acc[mt][nt][r] + bvv[nt];
        if (ACT) v = v > 0.f ? (v + 1.f) : __expf(v);  // elu(x)+1
        if (MODE == 0)      ((float*)Cout)[row * N + col] = v;
        else if (MODE == 1) ((u16*)Cout)[row * N + col] = f2bf(v);
        else {
          ((u16*)Cout)[col * (size_t)MROWS + row] = f2bf(v);  // C^T
          if (MODE == 3) csum[nt] += v;
        }
      }
  if (MODE == 3) {
    const int bidx = bRow >> 13;  // 256-row strip never crosses batch
#pragma unroll
    for (int nt = 0; nt < 4; nt++) {
      float s = csum[nt];
      s += __shfl_xor(s, 16, 64);
      s += __shfl_xor(s, 32, 64);   // quads hold the wave's 128-row col sum
      if ((lane >> 4) == 0)
        atomicAdd(&ksum[bidx * DM + bCol + wc * 64 + nt * 16 + ecol], s);
    }
  }
}

// KVT[m][d] partial = sum_n vT[m][n]*kT[d][n] over this block's 512-n chunk.
__global__ __launch_bounds__(256)
void kv_mfma_kernel(const u16* __restrict__ kT, const u16* __restrict__ vT,
                    float* __restrict__ part) {
  const int bh = blockIdx.y;
  const int b = bh >> 4, h = bh & 15;
  const size_t colbase = (size_t)b * NSEQ + blockIdx.x * CHUNKN;
  __shared__ u16 kts[64 * 64], vts[64 * 64];
  const int tid = threadIdx.x, lane = tid & 63, w = tid >> 6;
  const int wm = (w & 1) * 32, wd = (w >> 1) * 32;
  const int fr = lane & 15, fk = (lane >> 4) * 8;
  const int srow = lane >> 3, scol = (lane & 7) * 8;

  f32x4 acc[2][2] = {};

  for (int s = 0; s < CHUNKN / 64; s++) {
    const size_t cb = colbase + s * 64 + scol;
#pragma unroll
    for (int i = 0; i < 2; i++) {
      const int ii = w * 2 + i;
      const size_t grow = (size_t)(h * DK + ii * 8 + srow) * MROWS + cb;
      gl2lds16(vT + grow, vts + ii * 512);
      gl2lds16(kT + grow, kts + ii * 512);
    }
    __syncthreads();
#pragma unroll
    for (int ks = 0; ks < 2; ks++) {
      short8 af[2], bfr[2];
#pragma unroll
      for (int mt = 0; mt < 2; mt++)
        af[mt] = *(const short8*)(vts + (wm + mt * 16 + fr) * 64 + ks * 32 + fk);
#pragma unroll
      for (int dt = 0; dt < 2; dt++)
        bfr[dt] = *(const short8*)(kts + (wd + dt * 16 + fr) * 64 + ks * 32 + fk);
#pragma unroll
      for (int mt = 0; mt < 2; mt++)
#pragma unroll
        for (int dt = 0; dt < 2; dt++)
          acc[mt][dt] = __builtin_amdgcn_mfma_f32_16x16x32_bf16(af[mt], bfr[dt], acc[mt][dt], 0, 0, 0);
    }
    __syncthreads();
  }

  float* pp = part + ((size_t)blockIdx.x * 32 + bh) * (DK * DK);
  const int erow = (lane >> 4) * 4, ecol = lane & 15;
#pragma unroll
  for (int mt = 0; mt < 2; mt++)
#pragma unroll
    for (int dt = 0; dt < 2; dt++)
#pragma unroll
      for (int r = 0; r < 4; r++)
        pp[(wm + mt * 16 + erow + r) * DK + wd + dt * 16 + ecol] = acc[mt][dt][r];
}

// Reduce the 16 chunk-partials -> bf16 KVT[bh][m][d].
__global__ __launch_bounds__(256)
void kvt_reduce_kernel(const float* __restrict__ part, u16* __restrict__ kvt) {
  const int bh = blockIdx.x, t = threadIdx.x;
  const int i0 = t * 16;
  f32x4 s[4] = {};
  for (int c = 0; c < NCHUNKS; c++) {
    const f32x4* p = (const f32x4*)(part + ((size_t)c * 32 + bh) * (DK * DK) + i0);
#pragma unroll
    for (int q = 0; q < 4; q++) s[q] += p[q];
  }
  short8 o[2];
#pragma unroll
  for (int j = 0; j < 16; j++) o[j >> 3][j & 7] = (short)f2bf(s[j >> 2][j & 3]);
  *(short8*)(kvt + (size_t)bh * (DK * DK) + i0) = o[0];
  *(short8*)(kvt + (size_t)bh * (DK * DK) + i0 + 8) = o[1];
}

// out[n][m] = (q[n][:] . KVT[m][:]) / (q[n][:] . ksum + eps), per (b,h).
__global__ __launch_bounds__(256)
void attn_mfma_kernel(const u16* __restrict__ qp, const u16* __restrict__ kvt,
                      const float* __restrict__ ksum,
                      u16* __restrict__ ahi, u16* __restrict__ alo) {
  const int bh = blockIdx.y;
  const int b = bh >> 4, h = bh & 15;
  const int n0 = blockIdx.x * 128;
  const int tid = threadIdx.x, lane = tid & 63, w = tid >> 6;
  const int fr = lane & 15, fk = (lane >> 4) * 8;
  __shared__ float norm_lds[128];

  short8 bfr[4][2];
#pragma unroll
  for (int mt = 0; mt < 4; mt++)
#pragma unroll
    for (int ks = 0; ks < 2; ks++)
      bfr[mt][ks] = *(const short8*)(kvt + (size_t)bh * (DK * DK) + (mt * 16 + fr) * DK + ks * 32 + fk);

  float ksf[2][8];
#pragma unroll
  for (int ks = 0; ks < 2; ks++)
#pragma unroll
    for (int j = 0; j < 8; j++)
      ksf[ks][j] = ksum[b * DM + h * DK + ks * 32 + fk + j];

  const int nb = n0 + w * 32;
  short8 af[2][2];
#pragma unroll
  for (int nt = 0; nt < 2; nt++)
#pragma unroll
    for (int ks = 0; ks < 2; ks++)
      af[nt][ks] = *(const short8*)(qp + (size_t)(b * NSEQ + nb + nt * 16 + fr) * DM + h * DK + ks * 32 + fk);

  f32x4 acc[2][4] = {};
#pragma unroll
  for (int nt = 0; nt < 2; nt++)
#pragma unroll
    for (int mt = 0; mt < 4; mt++)
#pragma unroll
      for (int ks = 0; ks < 2; ks++)
        acc[nt][mt] = __builtin_amdgcn_mfma_f32_16x16x32_bf16(af[nt][ks], bfr[mt][ks], acc[nt][mt], 0, 0, 0);

#pragma unroll
  for (int nt = 0; nt < 2; nt++) {
    float p = 0.f;
#pragma unroll
    for (int ks = 0; ks < 2; ks++)
#pragma unroll
      for (int j = 0; j < 8; j++)
        p += bf2f((u16)af[nt][ks][j]) * ksf[ks][j];
    p += __shfl_xor(p, 16, 64);
    p += __shfl_xor(p, 32, 64);
    if ((lane >> 4) == 0) norm_lds[w * 32 + nt * 16 + fr] = p + EPS_F;
  }
  __syncthreads();

  const int erow = (lane >> 4) * 4, ec = lane & 15;
#pragma unroll
  for (int nt = 0; nt < 2; nt++) {
    float inv[4];
#pragma unroll
    for (int r = 0; r < 4; r++) inv[r] = 1.f / norm_lds[w * 32 + nt * 16 + erow + r];
#pragma unroll
    for (int mt = 0; mt < 4; mt++)
#pragma unroll
      for (int r = 0; r < 4; r++) {
        const float v = acc[nt][mt][r] * inv[r];
        const size_t o = (size_t)(b * NSEQ + nb + nt * 16 + erow + r) * DM + h * DK + mt * 16 + ec;
        const u16 hh = f2bf(v);
        ahi[o] = hh;
        alo[o] = f2bf(v - bf2f(hh));
      }
  }
}

extern "C" void kernel_launch(void* const* d_in, const int* in_sizes, int n_in,
                              void* d_out, int out_size, void* d_ws, size_t ws_size,
                              hipStream_t stream) {
  const float* query = (const float*)d_in[0];
  const float* key   = (const float*)d_in[1];
  const float* value = (const float*)d_in[2];
  const float* wq = (const float*)d_in[3];
  const float* bq = (const float*)d_in[4];
  const float* wk = (const float*)d_in[5];
  const float* bk = (const float*)d_in[6];
  const float* wv = (const float*)d_in[7];
  const float* bv = (const float*)d_in[8];
  const float* wo = (const float*)d_in[9];
  const float* bo = (const float*)d_in[10];
  float* out = (float*)d_out;

  constexpr size_t WELEM = (size_t)DM * DM;
  constexpr size_t AELEM = (size_t)MROWS * DM;

  char* p = (char*)d_ws;
  auto take = [&](size_t bytes) { char* q = p; p += (bytes + 255) & ~(size_t)255; return q; };
  u16* wqh = (u16*)take(WELEM * 2); u16* wql = (u16*)take(WELEM * 2);
  u16* wkh = (u16*)take(WELEM * 2); u16* wkl = (u16*)take(WELEM * 2);
  u16* wvh = (u16*)take(WELEM * 2); u16* wvl = (u16*)take(WELEM * 2);
  u16* woh = (u16*)take(WELEM * 2); u16* wol = (u16*)take(WELEM * 2);
  u16* chi = (u16*)take(AELEM * 2); u16* clo = (u16*)take(AELEM * 2);
  u16* qp  = (u16*)take(AELEM * 2);
  u16* kT  = (u16*)take(AELEM * 2);
  u16* vT  = (u16*)take(AELEM * 2);
  float* part = (float*)take((size_t)NCHUNKS * 32 * DK * DK * 4);
  float* ksum = (float*)take((size_t)BSZ * DM * 4);
  u16* kvt = (u16*)take((size_t)BSZ * NHEADS * DK * DK * 2);
  u16* ahi = chi; u16* alo = clo;   // chi/clo dead after V-GEMM reads them

  const dim3 blk(256);
  wsplit_kernel<<<1024, blk, 0, stream>>>(wq, wk, wv, wo, wqh, wql, wkh, wkl,
                                          wvh, wvl, woh, wol, ksum);

  const dim3 gblk(512);
  const dim3 ggrid(DM / 256, MROWS / 256);   // 4 x 64 = 256 blocks = 1/CU
  split_kernel<<<2048, blk, 0, stream>>>(query, chi, clo, (int)(AELEM / 4));
  gemm_mfma_kernel<1, 1><<<ggrid, gblk, 0, stream>>>(chi, clo, wqh, wql, bq, qp, nullptr);
  split_kernel<<<2048, blk, 0, stream>>>(key, chi, clo, (int)(AELEM / 4));
  gemm_mfma_kernel<1, 3><<<ggrid, gblk, 0, stream>>>(chi, clo, wkh, wkl, bk, kT, ksum);
  split_kernel<<<2048, blk, 0, stream>>>(value, chi, clo, (int)(AELEM / 4));
  gemm_mfma_kernel<0, 2><<<ggrid, gblk, 0, stream>>>(chi, clo, wvh, wvl, bv, vT, nullptr);

  kv_mfma_kernel<<<dim3(NCHUNKS, BSZ * NHEADS), blk, 0, stream>>>(kT, vT, part);
  kvt_reduce_kernel<<<32, blk, 0, stream>>>(part, kvt);
  attn_mfma_kernel<<<dim3(NSEQ / 128, BSZ * NHEADS), blk, 0, stream>>>(qp, kvt, ksum, ahi, alo);
  gemm_mfma_kernel<0, 0><<<ggrid, gblk, 0, stream>>>(ahi, alo, woh, wol, bo, out, nullptr);
}

// Round 3
// 647.268 us; speedup vs baseline: 1.1094x; 1.0202x over previous
//
#include <hip/hip_runtime.h>

#define DM 1024
#define NHEADS 16
#define DK 64
#define BSZ 2
#define NSEQ 8192
#define MROWS (BSZ*NSEQ)
#define NCHUNKS 16
#define CHUNKN 512

typedef unsigned short u16;
typedef __attribute__((ext_vector_type(8))) short short8;
typedef __attribute__((ext_vector_type(4))) float f32x4;

constexpr float EPS_F = 1e-6f;

__device__ __forceinline__ u16 f2bf(float x) {
  union { float f; unsigned u; } c; c.f = x;
  unsigned r = c.u + 0x7FFFu + ((c.u >> 16) & 1u);
  return (u16)(r >> 16);
}
__device__ __forceinline__ float bf2f(u16 h) {
  union { unsigned u; float f; } c; c.u = ((unsigned)h) << 16;
  return c.f;
}

typedef __attribute__((address_space(1))) const void gvoid_t;
typedef __attribute__((address_space(3))) void lvoid_t;
__device__ __forceinline__ void gl2lds16(const void* g, void* l) {
  // width=16: global_load_lds_dwordx4; LDS dst = wave-uniform base + lane*16
  __builtin_amdgcn_global_load_lds((gvoid_t*)g, (lvoid_t*)l, 16, 0, 0);
}

// fp32 -> (hi bf16, lo bf16) split.  hi = rne(x), lo = rne(x - hi).
__global__ __launch_bounds__(256)
void split_kernel(const float* __restrict__ src, u16* __restrict__ hi,
                  u16* __restrict__ lo, int n4) {
  int i = blockIdx.x * 256 + threadIdx.x;
  const int stride = gridDim.x * 256;
  for (; i < n4; i += stride) {
    const float4 v = ((const float4*)src)[i];
    const u16 h0 = f2bf(v.x), h1 = f2bf(v.y), h2 = f2bf(v.z), h3 = f2bf(v.w);
    const u16 l0 = f2bf(v.x - bf2f(h0)), l1 = f2bf(v.y - bf2f(h1));
    const u16 l2 = f2bf(v.z - bf2f(h2)), l3 = f2bf(v.w - bf2f(h3));
    ((ushort4*)hi)[i] = make_ushort4(h0, h1, h2, h3);
    ((ushort4*)lo)[i] = make_ushort4(l0, l1, l2, l3);
  }
}

// All four 1024x1024 weights split in one launch; also zeroes ksum (2048 f32).
__global__ __launch_bounds__(256)
void wsplit_kernel(const float* __restrict__ w0, const float* __restrict__ w1,
                   const float* __restrict__ w2, const float* __restrict__ w3,
                   u16* __restrict__ h0, u16* __restrict__ l0,
                   u16* __restrict__ h1, u16* __restrict__ l1,
                   u16* __restrict__ h2, u16* __restrict__ l2,
                   u16* __restrict__ h3, u16* __restrict__ l3,
                   float* __restrict__ ksum) {
  if (blockIdx.x < 8) ksum[blockIdx.x * 256 + threadIdx.x] = 0.f;
  constexpr int per = DM * DM / 4;   // 2^18 float4s per weight
  int i = blockIdx.x * 256 + threadIdx.x;
  const int stride = gridDim.x * 256;
  for (; i < 4 * per; i += stride) {
    const int w = i >> 18, j = i & (per - 1);
    const float* src = w == 0 ? w0 : w == 1 ? w1 : w == 2 ? w2 : w3;
    u16* hi = w == 0 ? h0 : w == 1 ? h1 : w == 2 ? h2 : h3;
    u16* lo = w == 0 ? l0 : w == 1 ? l1 : w == 2 ? l2 : l3;
    const float4 v = ((const float4*)src)[j];
    const u16 a0 = f2bf(v.x), a1 = f2bf(v.y), a2 = f2bf(v.z), a3 = f2bf(v.w);
    ((ushort4*)hi)[j] = make_ushort4(a0, a1, a2, a3);
    ((ushort4*)lo)[j] = make_ushort4(f2bf(v.x - bf2f(a0)), f2bf(v.y - bf2f(a1)),
                                     f2bf(v.z - bf2f(a2)), f2bf(v.w - bf2f(a3)));
  }
}

// C[M x N] = (Ahi+Alo)[M x K] @ (Whi+Wlo)[N x K]^T + bias via 3 bf16 MFMA
// passes (hi*hi + hi*lo + lo*hi).
//
// 256x256 tile, BK=32, 512 threads = 8 waves (2M x 4N), wave tile 128x64.
// Double-buffered LDS (128 KB, 1 block/CU); 8 global_load_lds at K-step top
// with COUNTED s_waitcnt vmcnt(8) (never 0 in-loop).
//
// K-step body is a software-pipelined read/MFMA roll with ONLY TWO barriers
// (top vmcnt-barrier + bottom lgkm(0)-closed barrier).  Intra-step barriers
// (round 2) were perf-only and forced both waves of a SIMD into lockstep
// ds_read latency stalls (MfmaUtil stuck at 41%).  Now each LDF group is
// issued UNDER the previous 16-MFMA cluster; compiler's counted lgkmcnt
// covers the rest.  Peak live frags stay 16 x b128 = 64 VGPR (no growth).
//
// T1: XCD-aware tile remap (bijective, 256%8==0): all 4 column-blocks of an
//     A-strip land on one XCD -> A staging L2-resident.
// T2: LDS swizzle kslot ^= (row>>1)&3 BOTH sides (source addr + read offset):
//     conflict-free b128 reads (SQ_LDS_BANK_CONFLICT == 0, r2).
// MODE: 0 = f32 normal, 1 = bf16 normal, 2 = bf16 transposed (C^T[N][M]),
//       3 = bf16 transposed + ksum column-sum atomics (for K projection).
template<int ACT, int MODE>
__global__ __launch_bounds__(512, 2)
void gemm_mfma_kernel(const u16* __restrict__ Ahi, const u16* __restrict__ Alo,
                      const u16* __restrict__ Whi, const u16* __restrict__ Wlo,
                      const float* __restrict__ bias, void* __restrict__ Cout,
                      float* __restrict__ ksum) {
  constexpr int K = DM, N = DM, BK = 32, NT = K / BK;
  // lds[buf][stream: Ahi 256rows | Alo | Whi | Wlo][row][32k swizzled]
  __shared__ u16 lds[2 * 4 * 8192];   // 128 KiB
  const int tid = threadIdx.x;
  const int lane = tid & 63, wv = tid >> 6;

  // XCD-aware remap: hw linear bid -> tile id so XCD c (= bid%8) owns
  // tiles [32c, 32c+32) = 8 consecutive A-strips x all 4 column-blocks.
  const int bid = blockIdx.y * gridDim.x + blockIdx.x;
  const int tile = (bid & 7) * 32 + (bid >> 3);
  const int bx = tile & 3, by = tile >> 2;
  const int bRow = by * 256, bCol = bx * 256;

  // --- staging: thread tid owns LDS u16 slot tid*8 of each 8KB chunk:
  //     row = tid>>2 (within 128-row half), linear kslot = tid&3.
  //     Source-side swizzle: fetch global kslot kg = (tid&3) ^ ((row>>1)&3)
  //     so the linear gl2lds write realizes the swizzled layout.
  const int srow = tid >> 2;
  const int kg = (tid & 3) ^ ((srow >> 1) & 3);
  const unsigned oA0 = (unsigned)(bRow + srow) * K + kg * 8;
  const unsigned oA1 = oA0 + 128u * K;
  const unsigned oW0 = (unsigned)(bCol + srow) * K + kg * 8;
  const unsigned oW1 = oW0 + 128u * K;

  // --- fragment reads: element (row, kslot=lane>>4) lives at u16 offset
  //     row*32 + ((lane>>4) ^ ((row>>1)&3))*8 ; (row>>1)&3 == (fr>>1)&3
  //     since all row bases are multiples of 16.
  const int wr = wv >> 2, wc = wv & 3;          // wave -> 128x64 sub-tile
  const int fr = lane & 15;
  const int axor = ((lane >> 4) ^ ((fr >> 1) & 3)) * 8;
  const int aoff = (wr * 128 + fr) * 32 + axor; // A-stream read base (u16)
  const int woff = (wc * 64 + fr) * 32 + axor;  // W-stream read base (u16)

  f32x4 acc[8][4] = {};

  auto STAGE = [&](int buf, int k0) {
    u16* b = lds + buf * 32768 + wv * 512;      // wave-uniform LDS dst
    gl2lds16(Ahi + oA0 + k0, b);
    gl2lds16(Ahi + oA1 + k0, b + 4096);
    gl2lds16(Alo + oA0 + k0, b + 8192);
    gl2lds16(Alo + oA1 + k0, b + 12288);
    gl2lds16(Whi + oW0 + k0, b + 16384);
    gl2lds16(Whi + oW1 + k0, b + 20480);
    gl2lds16(Wlo + oW0 + k0, b + 24576);
    gl2lds16(Wlo + oW1 + k0, b + 28672);
  };

  STAGE(0, 0);
  for (int t = 0; t < NT; ++t) {
    const int cur = t & 1;
    if (t + 1 < NT) {
      STAGE(cur ^ 1, (t + 1) * BK);
      // counted wait: 16 outstanding -> wait oldest 8 (cur buffer) only;
      // the 8 just-issued loads stay in flight under this K-step's compute.
      asm volatile("s_waitcnt vmcnt(8)" ::: "memory");
    } else {
      asm volatile("s_waitcnt vmcnt(0)" ::: "memory");
    }
    __builtin_amdgcn_s_barrier();

    const u16* A0 = lds + cur * 32768;   // Ahi rows 0..255 (swizzled k)
    const u16* A1 = A0 + 8192;           // Alo
    const u16* W0 = A0 + 16384;          // Whi
    const u16* W1 = A0 + 24576;          // Wlo

    short8 ah0[4], al0[4], ah1[4], al1[4], bh[4], bl[4];
    auto LDF = [&](short8 (&f)[4], const u16* s, int off) {
#pragma unroll
      for (int i = 0; i < 4; i++) f[i] = *(const short8*)(s + off + i * 512);
    };
    auto MM = [&](short8 (&af)[4], short8 (&bf)[4], int mb) {
      __builtin_amdgcn_s_setprio(1);
#pragma unroll
      for (int mt = 0; mt < 4; mt++)
#pragma unroll
        for (int nt = 0; nt < 4; nt++)
          acc[mb + mt][nt] = __builtin_amdgcn_mfma_f32_16x16x32_bf16(
              af[mt], bf[nt], acc[mb + mt][nt], 0, 0, 0);
      __builtin_amdgcn_s_setprio(0);
    };

    // Rolling pipeline: each LDF group issues under the previous MM cluster.
    LDF(ah0, A0, aoff);
    LDF(bh,  W0, woff);
    LDF(bl,  W1, woff);
    MM(ah0, bh, 0);
    LDF(al0, A1, aoff);
    MM(ah0, bl, 0);                 // ah0 dies -> regs recycle
    LDF(ah1, A0, aoff + 2048);
    MM(al0, bh, 0);                 // al0 dies
    LDF(al1, A1, aoff + 2048);
    MM(ah1, bh, 4);
    MM(ah1, bl, 4);                 // ah1, bl die
    MM(al1, bh, 4);
    // drain our ds_reads before the barrier that releases next STAGE into cur
    asm volatile("s_waitcnt lgkmcnt(0)" ::: "memory");
    __builtin_amdgcn_sched_barrier(0);
    __builtin_amdgcn_s_barrier();
  }

  // epilogue: C/D layout col = lane&15, row = (lane>>4)*4 + reg  [m89]
  const int erow = (lane >> 4) * 4;
  const int ecol = lane & 15;
  float bvv[4];
#pragma unroll
  for (int nt = 0; nt < 4; nt++) bvv[nt] = bias[bCol + wc * 64 + nt * 16 + ecol];
  float csum[4] = {0.f, 0.f, 0.f, 0.f};
#pragma unroll
  for (int mt = 0; mt < 8; mt++)
#pragma unroll
    for (int nt = 0; nt < 4; nt++)
#pragma unroll
      for (int r = 0; r < 4; r++) {
        const size_t row = (size_t)bRow + wr * 128 + mt * 16 + erow + r;
        const size_t col = (size_t)bCol + wc * 64 + nt * 16 + ecol;
        float v = acc[mt][nt][r] + bvv[nt];
        if (ACT) v = v > 0.f ? (v + 1.f) : __expf(v);  // elu(x)+1
        if (MODE == 0)      ((float*)Cout)[row * N + col] = v;
        else if (MODE == 1) ((u16*)Cout)[row * N + col] = f2bf(v);
        else {
          ((u16*)Cout)[col * (size_t)MROWS + row] = f2bf(v);  // C^T
          if (MODE == 3) csum[nt] += v;
        }
      }
  if (MODE == 3) {
    const int bidx = bRow >> 13;  // 256-row strip never crosses batch
#pragma unroll
    for (int nt = 0; nt < 4; nt++) {
      float s = csum[nt];
      s += __shfl_xor(s, 16, 64);
      s += __shfl_xor(s, 32, 64);   // quads hold the wave's 128-row col sum
      if ((lane >> 4) == 0)
        atomicAdd(&ksum[bidx * DM + bCol + wc * 64 + nt * 16 + ecol], s);
    }
  }
}

// KVT[m][d] partial = sum_n vT[m][n]*kT[d][n] over this block's 512-n chunk.
__global__ __launch_bounds__(256)
void kv_mfma_kernel(const u16* __restrict__ kT, const u16* __restrict__ vT,
                    float* __restrict__ part) {
  const int bh = blockIdx.y;
  const int b = bh >> 4, h = bh & 15;
  const size_t colbase = (size_t)b * NSEQ + blockIdx.x * CHUNKN;
  __shared__ u16 kts[64 * 64], vts[64 * 64];
  const int tid = threadIdx.x, lane = tid & 63, w = tid >> 6;
  const int wm = (w & 1) * 32, wd = (w >> 1) * 32;
  const int fr = lane & 15, fk = (lane >> 4) * 8;
  const int srow = lane >> 3, scol = (lane & 7) * 8;

  f32x4 acc[2][2] = {};

  for (int s = 0; s < CHUNKN / 64; s++) {
    const size_t cb = colbase + s * 64 + scol;
#pragma unroll
    for (int i = 0; i < 2; i++) {
      const int ii = w * 2 + i;
      const size_t grow = (size_t)(h * DK + ii * 8 + srow) * MROWS + cb;
      gl2lds16(vT + grow, vts + ii * 512);
      gl2lds16(kT + grow, kts + ii * 512);
    }
    __syncthreads();
#pragma unroll
    for (int ks = 0; ks < 2; ks++) {
      short8 af[2], bfr[2];
#pragma unroll
      for (int mt = 0; mt < 2; mt++)
        af[mt] = *(const short8*)(vts + (wm + mt * 16 + fr) * 64 + ks * 32 + fk);
#pragma unroll
      for (int dt = 0; dt < 2; dt++)
        bfr[dt] = *(const short8*)(kts + (wd + dt * 16 + fr) * 64 + ks * 32 + fk);
#pragma unroll
      for (int mt = 0; mt < 2; mt++)
#pragma unroll
        for (int dt = 0; dt < 2; dt++)
          acc[mt][dt] = __builtin_amdgcn_mfma_f32_16x16x32_bf16(af[mt], bfr[dt], acc[mt][dt], 0, 0, 0);
    }
    __syncthreads();
  }

  float* pp = part + ((size_t)blockIdx.x * 32 + bh) * (DK * DK);
  const int erow = (lane >> 4) * 4, ecol = lane & 15;
#pragma unroll
  for (int mt = 0; mt < 2; mt++)
#pragma unroll
    for (int dt = 0; dt < 2; dt++)
#pragma unroll
      for (int r = 0; r < 4; r++)
        pp[(wm + mt * 16 + erow + r) * DK + wd + dt * 16 + ecol] = acc[mt][dt][r];
}

// Reduce the 16 chunk-partials -> bf16 KVT[bh][m][d].
__global__ __launch_bounds__(256)
void kvt_reduce_kernel(const float* __restrict__ part, u16* __restrict__ kvt) {
  const int bh = blockIdx.x, t = threadIdx.x;
  const int i0 = t * 16;
  f32x4 s[4] = {};
  for (int c = 0; c < NCHUNKS; c++) {
    const f32x4* p = (const f32x4*)(part + ((size_t)c * 32 + bh) * (DK * DK) + i0);
#pragma unroll
    for (int q = 0; q < 4; q++) s[q] += p[q];
  }
  short8 o[2];
#pragma unroll
  for (int j = 0; j < 16; j++) o[j >> 3][j & 7] = (short)f2bf(s[j >> 2][j & 3]);
  *(short8*)(kvt + (size_t)bh * (DK * DK) + i0) = o[0];
  *(short8*)(kvt + (size_t)bh * (DK * DK) + i0 + 8) = o[1];
}

// out[n][m] = (q[n][:] . KVT[m][:]) / (q[n][:] . ksum + eps), per (b,h).
__global__ __launch_bounds__(256)
void attn_mfma_kernel(const u16* __restrict__ qp, const u16* __restrict__ kvt,
                      const float* __restrict__ ksum,
                      u16* __restrict__ ahi, u16* __restrict__ alo) {
  const int bh = blockIdx.y;
  const int b = bh >> 4, h = bh & 15;
  const int n0 = blockIdx.x * 128;
  const int tid = threadIdx.x, lane = tid & 63, w = tid >> 6;
  const int fr = lane & 15, fk = (lane >> 4) * 8;
  __shared__ float norm_lds[128];

  short8 bfr[4][2];
#pragma unroll
  for (int mt = 0; mt < 4; mt++)
#pragma unroll
    for (int ks = 0; ks < 2; ks++)
      bfr[mt][ks] = *(const short8*)(kvt + (size_t)bh * (DK * DK) + (mt * 16 + fr) * DK + ks * 32 + fk);

  float ksf[2][8];
#pragma unroll
  for (int ks = 0; ks < 2; ks++)
#pragma unroll
    for (int j = 0; j < 8; j++)
      ksf[ks][j] = ksum[b * DM + h * DK + ks * 32 + fk + j];

  const int nb = n0 + w * 32;
  short8 af[2][2];
#pragma unroll
  for (int nt = 0; nt < 2; nt++)
#pragma unroll
    for (int ks = 0; ks < 2; ks++)
      af[nt][ks] = *(const short8*)(qp + (size_t)(b * NSEQ + nb + nt * 16 + fr) * DM + h * DK + ks * 32 + fk);

  f32x4 acc[2][4] = {};
#pragma unroll
  for (int nt = 0; nt < 2; nt++)
#pragma unroll
    for (int mt = 0; mt < 4; mt++)
#pragma unroll
      for (int ks = 0; ks < 2; ks++)
        acc[nt][mt] = __builtin_amdgcn_mfma_f32_16x16x32_bf16(af[nt][ks], bfr[mt][ks], acc[nt][mt], 0, 0, 0);

#pragma unroll
  for (int nt = 0; nt < 2; nt++) {
    float p = 0.f;
#pragma unroll
    for (int ks = 0; ks < 2; ks++)
#pragma unroll
      for (int j = 0; j < 8; j++)
        p += bf2f((u16)af[nt][ks][j]) * ksf[ks][j];
    p += __shfl_xor(p, 16, 64);
    p += __shfl_xor(p, 32, 64);
    if ((lane >> 4) == 0) norm_lds[w * 32 + nt * 16 + fr] = p + EPS_F;
  }
  __syncthreads();

  const int erow = (lane >> 4) * 4, ec = lane & 15;
#pragma unroll
  for (int nt = 0; nt < 2; nt++) {
    float inv[4];
#pragma unroll
    for (int r = 0; r < 4; r++) inv[r] = 1.f / norm_lds[w * 32 + nt * 16 + erow + r];
#pragma unroll
    for (int mt = 0; mt < 4; mt++)
#pragma unroll
      for (int r = 0; r < 4; r++) {
        const float v = acc[nt][mt][r] * inv[r];
        const size_t o = (size_t)(b * NSEQ + nb + nt * 16 + erow + r) * DM + h * DK + mt * 16 + ec;
        const u16 hh = f2bf(v);
        ahi[o] = hh;
        alo[o] = f2bf(v - bf2f(hh));
      }
  }
}

extern "C" void kernel_launch(void* const* d_in, const int* in_sizes, int n_in,
                              void* d_out, int out_size, void* d_ws, size_t ws_size,
                              hipStream_t stream) {
  const float* query = (const float*)d_in[0];
  const float* key   = (const float*)d_in[1];
  const float* value = (const float*)d_in[2];
  const float* wq = (const float*)d_in[3];
  const float* bq = (const float*)d_in[4];
  const float* wk = (const float*)d_in[5];
  const float* bk = (const float*)d_in[6];
  const float* wv = (const float*)d_in[7];
  const float* bv = (const float*)d_in[8];
  const float* wo = (const float*)d_in[9];
  const float* bo = (const float*)d_in[10];
  float* out = (float*)d_out;

  constexpr size_t WELEM = (size_t)DM * DM;
  constexpr size_t AELEM = (size_t)MROWS * DM;

  char* p = (char*)d_ws;
  auto take = [&](size_t bytes) { char* q = p; p += (bytes + 255) & ~(size_t)255; return q; };
  u16* wqh = (u16*)take(WELEM * 2); u16* wql = (u16*)take(WELEM * 2);
  u16* wkh = (u16*)take(WELEM * 2); u16* wkl = (u16*)take(WELEM * 2);
  u16* wvh = (u16*)take(WELEM * 2); u16* wvl = (u16*)take(WELEM * 2);
  u16* woh = (u16*)take(WELEM * 2); u16* wol = (u16*)take(WELEM * 2);
  u16* chi = (u16*)take(AELEM * 2); u16* clo = (u16*)take(AELEM * 2);
  u16* qp  = (u16*)take(AELEM * 2);
  u16* kT  = (u16*)take(AELEM * 2);
  u16* vT  = (u16*)take(AELEM * 2);
  float* part = (float*)take((size_t)NCHUNKS * 32 * DK * DK * 4);
  float* ksum = (float*)take((size_t)BSZ * DM * 4);
  u16* kvt = (u16*)take((size_t)BSZ * NHEADS * DK * DK * 2);
  u16* ahi = chi; u16* alo = clo;   // chi/clo dead after V-GEMM reads them

  const dim3 blk(256);
  wsplit_kernel<<<1024, blk, 0, stream>>>(wq, wk, wv, wo, wqh, wql, wkh, wkl,
                                          wvh, wvl, woh, wol, ksum);

  const dim3 gblk(512);
  const dim3 ggrid(DM / 256, MROWS / 256);   // 4 x 64 = 256 blocks = 1/CU
  split_kernel<<<2048, blk, 0, stream>>>(query, chi, clo, (int)(AELEM / 4));
  gemm_mfma_kernel<1, 1><<<ggrid, gblk, 0, stream>>>(chi, clo, wqh, wql, bq, qp, nullptr);
  split_kernel<<<2048, blk, 0, stream>>>(key, chi, clo, (int)(AELEM / 4));
  gemm_mfma_kernel<1, 3><<<ggrid, gblk, 0, stream>>>(chi, clo, wkh, wkl, bk, kT, ksum);
  split_kernel<<<2048, blk, 0, stream>>>(value, chi, clo, (int)(AELEM / 4));
  gemm_mfma_kernel<0, 2><<<ggrid, gblk, 0, stream>>>(chi, clo, wvh, wvl, bv, vT, nullptr);

  kv_mfma_kernel<<<dim3(NCHUNKS, BSZ * NHEADS), blk, 0, stream>>>(kT, vT, part);
  kvt_reduce_kernel<<<32, blk, 0, stream>>>(part, kvt);
  attn_mfma_kernel<<<dim3(NSEQ / 128, BSZ * NHEADS), blk, 0, stream>>>(qp, kvt, ksum, ahi, alo);
  gemm_mfma_kernel<0, 0><<<ggrid, gblk, 0, stream>>>(ahi, alo, woh, wol, bo, out, nullptr);
}